// Round 1
// baseline (71.227 us; speedup 1.0000x reference)
//
#include <hip/hip_runtime.h>

#define TABLE_MASK 0x7FFFFu
#define RES 512.0f
#define HPI2 2654435761u
#define HPI3 805459861u

__global__ __launch_bounds__(256) void ingp_gather_kernel(
    const float* __restrict__ x,
    const float2* __restrict__ table,
    float2* __restrict__ out,
    int n)
{
    int i = blockIdx.x * blockDim.x + threadIdx.x;
    if (i >= n) return;

    // coords (layout [N,3] row-major)
    float xs = x[3 * i + 0] * RES;
    float ys = x[3 * i + 1] * RES;
    float zs = x[3 * i + 2] * RES;

    float xf = floorf(xs), yf = floorf(ys), zf = floorf(zs);

    // weights — mirror reference: w = 1 - |xs - corner_f|
    float wx0 = 1.0f - (xs - xf);
    float wx1 = 1.0f - fabsf(xs - (xf + 1.0f));
    float wy0 = 1.0f - (ys - yf);
    float wy1 = 1.0f - fabsf(ys - (yf + 1.0f));
    float wz0 = 1.0f - (zs - zf);
    float wz1 = 1.0f - fabsf(zs - (zf + 1.0f));

    // hash terms: low 19 bits of wrapping u32 mults == low 19 bits of int64 mults
    unsigned cx = (unsigned)(int)xf;
    unsigned cy = (unsigned)(int)yf;
    unsigned cz = (unsigned)(int)zf;
    unsigned hx0 = cx;                       // * PI1 (=1)
    unsigned hx1 = cx + 1u;
    unsigned hy0 = cy * HPI2;
    unsigned hy1 = (cy + 1u) * HPI2;
    unsigned hz0 = cz * HPI3;
    unsigned hz1 = (cz + 1u) * HPI3;

    // corner order: c = ix*4 + iy*2 + iz  (matches OFFSETS nesting)
    unsigned idx0 = (hx0 ^ hy0 ^ hz0) & TABLE_MASK;
    unsigned idx1 = (hx0 ^ hy0 ^ hz1) & TABLE_MASK;
    unsigned idx2 = (hx0 ^ hy1 ^ hz0) & TABLE_MASK;
    unsigned idx3 = (hx0 ^ hy1 ^ hz1) & TABLE_MASK;
    unsigned idx4 = (hx1 ^ hy0 ^ hz0) & TABLE_MASK;
    unsigned idx5 = (hx1 ^ hy0 ^ hz1) & TABLE_MASK;
    unsigned idx6 = (hx1 ^ hy1 ^ hz0) & TABLE_MASK;
    unsigned idx7 = (hx1 ^ hy1 ^ hz1) & TABLE_MASK;

    // issue all 8 gathers up front (independent loads -> ILP hides latency)
    float2 f0 = table[idx0];
    float2 f1 = table[idx1];
    float2 f2 = table[idx2];
    float2 f3 = table[idx3];
    float2 f4 = table[idx4];
    float2 f5 = table[idx5];
    float2 f6 = table[idx6];
    float2 f7 = table[idx7];

    float w0 = wx0 * wy0 * wz0;
    float w1 = wx0 * wy0 * wz1;
    float w2 = wx0 * wy1 * wz0;
    float w3 = wx0 * wy1 * wz1;
    float w4 = wx1 * wy0 * wz0;
    float w5 = wx1 * wy0 * wz1;
    float w6 = wx1 * wy1 * wz0;
    float w7 = wx1 * wy1 * wz1;

    float ox = f0.x * w0 + f1.x * w1 + f2.x * w2 + f3.x * w3
             + f4.x * w4 + f5.x * w5 + f6.x * w6 + f7.x * w7;
    float oy = f0.y * w0 + f1.y * w1 + f2.y * w2 + f3.y * w3
             + f4.y * w4 + f5.y * w5 + f6.y * w6 + f7.y * w7;

    out[i] = make_float2(ox, oy);
}

extern "C" void kernel_launch(void* const* d_in, const int* in_sizes, int n_in,
                              void* d_out, int out_size, void* d_ws, size_t ws_size,
                              hipStream_t stream) {
    const float*  x     = (const float*)d_in[0];
    const float2* table = (const float2*)d_in[1];
    float2*       out   = (float2*)d_out;
    int n = in_sizes[0] / 3;   // [N,3] flat

    int block = 256;
    int grid = (n + block - 1) / block;
    ingp_gather_kernel<<<grid, block, 0, stream>>>(x, table, out, n);
}